// Round 5
// baseline (560.166 us; speedup 1.0000x reference)
//
#include <hip/hip_runtime.h>
#include <hip/hip_fp16.h>
#include <cstdint>
#include <cstddef>

#define EPS_BN 1e-5f
#define NSLICE 16          // stats accumulator shards (power of 2)
#define NCHUNK 16          // src chunks per neighbor list (power of 2)

static inline int cdiv(int a, int b) { return (a + b - 1) / b; }

using half8   = __attribute__((ext_vector_type(8))) _Float16;
using floatx4 = __attribute__((ext_vector_type(4))) float;
using u32x4   = __attribute__((ext_vector_type(4))) unsigned int;

__device__ __forceinline__ float atomAddF(float* p, float v) {
    return unsafeAtomicAdd(p, v);   // HW global_atomic_add_f32 on gfx950
}

// ================= bucketed CSR build =================
// bucket = dst >> 9 (512 nodes per bucket); NBUCK <= 256 (n <= 131072) required.
// pairs[] entries are packed: (dstLow9 << 17) | src17.
// csr is sub-sorted by (dst, src>>sh): 16 chunks per node, endoff[v*16+c] = cumulative end.

__global__ __launch_bounds__(256) void k_hist(const int* __restrict__ dst, int E,
                                              int NBLK, int NBUCK, int* __restrict__ H) {
    __shared__ int h[256];
    int t = threadIdx.x;
    h[t] = 0;
    __syncthreads();
    int base = blockIdx.x * 4096;
#pragma unroll
    for (int j = 0; j < 16; ++j) {
        int e = base + j * 256 + t;
        if (e < E) atomicAdd(&h[dst[e] >> 9], 1);
    }
    __syncthreads();
    if (t < NBUCK) H[t * NBLK + blockIdx.x] = h[t];
}

__global__ __launch_bounds__(256) void k_scan_reduce(const int* __restrict__ in, int m,
                                                     int* __restrict__ bsum) {
    int base = blockIdx.x * 1024;
    int t = threadIdx.x;
    int s = 0;
#pragma unroll
    for (int i = 0; i < 4; ++i) {
        int idx = base + t * 4 + i;
        if (idx < m) s += in[idx];
    }
    __shared__ int sm[256];
    sm[t] = s;
    __syncthreads();
    for (int off = 128; off > 0; off >>= 1) {
        if (t < off) sm[t] += sm[t + off];
        __syncthreads();
    }
    if (t == 0) bsum[blockIdx.x] = sm[0];
}

__global__ void k_scan_bsum(int* __restrict__ bsum, int nb) {
    if (threadIdx.x == 0 && blockIdx.x == 0) {
        int acc = 0;
        for (int i = 0; i < nb; ++i) { int v = bsum[i]; bsum[i] = acc; acc += v; }
    }
}

__global__ __launch_bounds__(256) void k_scan_final(const int* __restrict__ in, int m,
                                                    const int* __restrict__ bsum,
                                                    int* __restrict__ outS) {
    int base = blockIdx.x * 1024;
    int t = threadIdx.x;
    int v[4];
    int s = 0;
#pragma unroll
    for (int i = 0; i < 4; ++i) {
        int idx = base + t * 4 + i;
        v[i] = (idx < m) ? in[idx] : 0;
        s += v[i];
    }
    __shared__ int sm[256];
    sm[t] = s;
    __syncthreads();
    for (int off = 1; off < 256; off <<= 1) {
        int x = (t >= off) ? sm[t - off] : 0;
        __syncthreads();
        sm[t] += x;
        __syncthreads();
    }
    int excl = sm[t] - s + bsum[blockIdx.x];
#pragma unroll
    for (int i = 0; i < 4; ++i) {
        int idx = base + t * 4 + i;
        if (idx < m) { outS[idx] = excl; excl += v[i]; }
    }
}

__global__ __launch_bounds__(256) void k_bucket(const int* __restrict__ src,
                                                const int* __restrict__ dst, int E,
                                                int NBLK, int NBUCK,
                                                const int* __restrict__ S,
                                                unsigned* __restrict__ pairs) {
    __shared__ int cur[256];
    int t = threadIdx.x;
    if (t < NBUCK) cur[t] = S[t * NBLK + blockIdx.x];
    __syncthreads();
    int base = blockIdx.x * 4096;
#pragma unroll
    for (int j = 0; j < 16; ++j) {
        int e = base + j * 256 + t;
        if (e < E) {
            unsigned s = (unsigned)src[e];
            unsigned d = (unsigned)dst[e];
            int p = atomicAdd(&cur[d >> 9], 1);
            pairs[p] = ((d & 511u) << 17) | s;
        }
    }
}

// counting sort by key = (dstLow9 << 4) | (src >> sh); 8192 keys per bucket.
__global__ __launch_bounds__(256) void k_build(const unsigned* __restrict__ pairs,
                                               const int* __restrict__ S,
                                               int NBLK, int NBUCK, int n, int E, int sh,
                                               int* __restrict__ endoff,
                                               float* __restrict__ dinv,
                                               int* __restrict__ csr) {
    int b = blockIdx.x;
    int nbase = b << 9;
    int bstart = S[b * NBLK];
    int bend = (b == NBUCK - 1) ? E : S[(b + 1) * NBLK];
    int t = threadIdx.x;
    __shared__ int sdeg[8192];
    __shared__ int scur[8192];
    __shared__ int stmp[256];
#pragma unroll
    for (int i = 0; i < 32; ++i) sdeg[t + i * 256] = 0;
    __syncthreads();
    for (int e = bstart + t; e < bend; e += 256) {
        unsigned p = pairs[e];
        int key = (int)((p >> 17) << 4) | (int)((p & 0x1FFFFu) >> sh);
        atomicAdd(&sdeg[key], 1);
    }
    __syncthreads();
    int loc[32];
    int ls = 0;
#pragma unroll
    for (int i = 0; i < 32; ++i) { loc[i] = sdeg[t * 32 + i]; ls += loc[i]; }
    stmp[t] = ls;
    __syncthreads();
    for (int off = 1; off < 256; off <<= 1) {
        int x = (t >= off) ? stmp[t - off] : 0;
        __syncthreads();
        stmp[t] += x;
        __syncthreads();
    }
    int run = bstart + stmp[t] - ls;
    int d0 = 0, d1 = 0;
    int v0 = nbase + 2 * t, v1 = v0 + 1;
#pragma unroll
    for (int i = 0; i < 32; ++i) {
        scur[t * 32 + i] = run;
        int e_ = run + loc[i];
        int v = (i < 16) ? v0 : v1;
        if (v < n) endoff[(size_t)v * NCHUNK + (i & 15)] = e_;
        run = e_;
        if (i < 16) d0 += loc[i]; else d1 += loc[i];
    }
    if (v0 < n) dinv[v0] = rsqrtf((float)(d0 + 1));
    if (v1 < n) dinv[v1] = rsqrtf((float)(d1 + 1));
    __syncthreads();
    for (int e = bstart + t; e < bend; e += 256) {
        unsigned p = pairs[e];
        int key = (int)((p >> 17) << 4) | (int)((p & 0x1FFFFu) >> sh);
        int pos = atomicAdd(&scur[key], 1);
        csr[pos] = (int)(p & 0x1FFFFu);
    }
}

// ================= prep: x->f16*dinv, weights->f16 transposed, stats zero ========
__global__ __launch_bounds__(256) void k_prep(const float* __restrict__ x,
                                              const float* __restrict__ dinv,
                                              const float* __restrict__ W1,
                                              const float* __restrict__ W2,
                                              const float* __restrict__ W3,
                                              __half* __restrict__ xh,
                                              __half* __restrict__ Wt1,
                                              __half* __restrict__ Wt2,
                                              __half* __restrict__ Wt3,
                                              float* __restrict__ stats, int n) {
    int idx = blockIdx.x * 256 + threadIdx.x;
    int nx = n * 16;
    if (idx < nx) {                          // x -> f16, pre-scaled by dinv (8-half chunks)
        int row = idx >> 4;
        float dv = dinv[row];
        const float4* p = (const float4*)x + (size_t)idx * 2;
        float4 a = p[0], b = p[1];
        uint4 o; __half2* oh = (__half2*)&o;
        oh[0] = __floats2half2_rn(a.x * dv, a.y * dv);
        oh[1] = __floats2half2_rn(a.z * dv, a.w * dv);
        oh[2] = __floats2half2_rn(b.x * dv, b.y * dv);
        oh[3] = __floats2half2_rn(b.z * dv, b.w * dv);
        ((uint4*)xh)[idx] = o;
        return;
    }
    int r = idx - nx;
    if (r < 32768) {                         // W1: 128x256
        int k = r >> 8, c = r & 255;
        Wt1[c * 128 + k] = __float2half(W1[r]);
    } else if (r < 98304) {                  // W2: 256x256
        int r2 = r - 32768;
        int k = r2 >> 8, c = r2 & 255;
        Wt2[c * 256 + k] = __float2half(W2[r2]);
    } else if (r < 131072) {                 // W3: 256x128
        int r2 = r - 98304;
        int k = r2 >> 7, c = r2 & 127;
        Wt3[c * 256 + k] = __float2half(W3[r2]);
    } else if (r < 131072 + NSLICE * 256 * 6) {
        stats[r - 131072] = 0.f;             // zero all 3 layers' sliced sums/sqs
    }
}

// ================= CSR gather, feature-sliced, NT single-use streams ============
// csr lists sorted by src>>sh -> linear walk reads monotone ~0.8MB src windows.
// Neighbor-row (P window) loads stay CACHED -- that's the reuse we protect.
// Single-use streams (self row, endoff, S-output store) are NON-TEMPORAL so
// they don't evict the P window from the 4MB per-XCD L2 (R4 post-mortem:
// stream pollution, not phase drift, is what holds re-fetch at ~2.5x).
__device__ __forceinline__ void acc8(float* acc, uint4 d) {
    const __half2* h = (const __half2*)&d;
#pragma unroll
    for (int j = 0; j < 4; ++j) {
        float2 f = __half22float2(h[j]);
        acc[2 * j] += f.x; acc[2 * j + 1] += f.y;
    }
}

template<int D>
__device__ __forceinline__ void gseg(const __half* __restrict__ Pb,
                                     const int* __restrict__ csr,
                                     int i, int end, float* acc) {
    int rem = (end - i) & 3;
    if (rem & 2) {
        uint4 d0 = *(const uint4*)(Pb + (size_t)csr[i] * D);
        uint4 d1 = *(const uint4*)(Pb + (size_t)csr[i + 1] * D);
        acc8(acc, d0); acc8(acc, d1);
        i += 2;
    }
    if (rem & 1) {
        uint4 d0 = *(const uint4*)(Pb + (size_t)csr[i] * D);
        acc8(acc, d0);
        ++i;
    }
    if (i < end) {                           // multiple of 4 remaining
        uint4 a[4];
#pragma unroll
        for (int u = 0; u < 4; ++u)
            a[u] = *(const uint4*)(Pb + (size_t)csr[i + u] * D);
        for (i += 4; i < end; i += 4) {
            uint4 b[4];
#pragma unroll
            for (int u = 0; u < 4; ++u)
                b[u] = *(const uint4*)(Pb + (size_t)csr[i + u] * D);
#pragma unroll
            for (int u = 0; u < 4; ++u) acc8(acc, a[u]);
#pragma unroll
            for (int u = 0; u < 4; ++u) a[u] = b[u];
        }
#pragma unroll
        for (int u = 0; u < 4; ++u) acc8(acc, a[u]);
    }
}

template<int D, bool STATS>
__global__ __launch_bounds__(256, 8) void k_gather5(const int* __restrict__ csr,
                                                    const int* __restrict__ endoff,
                                                    const __half* __restrict__ P,
                                                    const float* __restrict__ dinv,
                                                    __half* __restrict__ S, int n,
                                                    float* __restrict__ sums,
                                                    float* __restrict__ sqs) {
    constexpr int NSL = D / 64;              // 128B slices per row (2 or 4)
    __shared__ float red[STATS ? 2048 : 1];
    int bid = blockIdx.x;
    int x8 = bid & 7;
    int slice, gidx;
    if (NSL == 4) { slice = x8 >> 1; gidx = (bid >> 3) * 2 + (x8 & 1); }
    else          { slice = x8 >> 2; gidx = (bid >> 3) * 4 + (x8 & 3); }
    int Gn = (n + 31) >> 5;
    if (gidx >= Gn) return;                  // whole block exits (uniform)
    int t = threadIdx.x;
    int lane = t & 7;                        // 16B sub-slice within 128B
    int sub = t >> 3;                        // node within block (32 nodes)
    int v = gidx * 32 + sub;
    // clock-phased start window: ~1us per window at 100MHz REFCLK
    int c0 = (int)((wall_clock64() / 100ull) & (unsigned long long)(NCHUNK - 1));
    const __half* Pb = P + (size_t)slice * 64 + lane * 8;
    float ov[8];
#pragma unroll
    for (int j = 0; j < 8; ++j) ov[j] = 0.f;
    if (v < n) {
        float acc[8];
        {
            // self term: single-use stream -> non-temporal
            u32x4 sv = __builtin_nontemporal_load((const u32x4*)(Pb + (size_t)v * D));
            const __half2* h = (const __half2*)&sv;
#pragma unroll
            for (int j = 0; j < 4; ++j) {
                float2 f = __half22float2(h[j]);
                acc[2 * j] = f.x; acc[2 * j + 1] = f.y;
            }
        }
        size_t i0 = (size_t)v * NCHUNK;
        int beg = (i0 == 0) ? 0 : __builtin_nontemporal_load(endoff + i0 - 1);
        int end = __builtin_nontemporal_load(endoff + i0 + NCHUNK - 1);
        int mid = (c0 == 0) ? beg : __builtin_nontemporal_load(endoff + i0 + c0 - 1);
        gseg<D>(Pb, csr, mid, end, acc);     // [mid, end)
        gseg<D>(Pb, csr, beg, mid, acc);     // [beg, mid)
        float dv = dinv[v];
        uint4 o; __half2* oh = (__half2*)&o;
#pragma unroll
        for (int j = 0; j < 4; ++j) {
            float a0 = acc[2 * j] * dv, a1 = acc[2 * j + 1] * dv;
            oh[j] = __floats2half2_rn(a0, a1);
            ov[2 * j] = a0; ov[2 * j + 1] = a1;
        }
        // output: single-use stream -> non-temporal store
        __builtin_nontemporal_store(*(const u32x4*)&o,
                                    (u32x4*)(S + (size_t)v * D + slice * 64 + lane * 8));
    }
    if (STATS) {
        int shard = bid & (NSLICE - 1);
#pragma unroll
        for (int j = 0; j < 8; ++j) red[t * 8 + j] = ov[j];
        __syncthreads();
        if (t < 64) {                        // col-in-slice = t = lane*8+j
            int ln = t >> 3, j = t & 7;
            float ts = 0.f;
#pragma unroll
            for (int s = 0; s < 32; ++s) ts += red[(s * 8 + ln) * 8 + j];
            atomAddF(&sums[shard * 256 + slice * 64 + t], ts);
        }
        __syncthreads();
#pragma unroll
        for (int j = 0; j < 8; ++j) red[t * 8 + j] = ov[j] * ov[j];
        __syncthreads();
        if (t < 64) {
            int ln = t >> 3, j = t & 7;
            float tq = 0.f;
#pragma unroll
            for (int s = 0; s < 32; ++s) tq += red[(s * 8 + ln) * 8 + j];
            atomAddF(&sqs[shard * 256 + slice * 64 + t], tq);
        }
    }
}

// ================= MFMA GEMM: 128x128 tile, 2x2 waves of 64x64 each =============
template<int K, int NC, bool SCALE, bool BNIN, bool STATS>
__global__ __launch_bounds__(256) void k_gemm_mfma(const __half* __restrict__ A,
                                                   const __half* __restrict__ Wt,
                                                   const float* __restrict__ dinv,
                                                   const float* __restrict__ isum,
                                                   const float* __restrict__ isq,
                                                   const float* __restrict__ g,
                                                   const float* __restrict__ beta,
                                                   float* __restrict__ osum,
                                                   float* __restrict__ osq,
                                                   __half* __restrict__ C, int n) {
    constexpr int LDA = 40;
    __shared__ _Float16 As[128 * LDA];
    __shared__ _Float16 Bs[128 * LDA];
    __shared__ float ssc[BNIN ? K : 1];
    __shared__ float ssh[BNIN ? K : 1];
    __shared__ float scs[STATS ? 128 : 1];
    __shared__ float scq[STATS ? 128 : 1];
    int tid = threadIdx.x;
    if (BNIN) {
        float nf = (float)n;
        for (int i = tid; i < K; i += 256) {
            float su = 0.f, sq = 0.f;
#pragma unroll
            for (int s = 0; s < NSLICE; ++s) {
                su += isum[s * 256 + i];
                sq += isq[s * 256 + i];
            }
            float mu = su / nf;
            float var = sq / nf - mu * mu;
            float sc = g[i] * rsqrtf(var + EPS_BN);
            ssc[i] = sc; ssh[i] = beta[i] - mu * sc;
        }
        __syncthreads();
    }
    int wave = tid >> 6, lane = tid & 63;
    int wr = wave >> 1, wc = wave & 1;        // 2x2 wave grid, 64x64 per wave
    int q = lane >> 4, l16 = lane & 15;
    int row0 = blockIdx.x * 128;
    int col0 = blockIdx.y * 128;
    floatx4 acc[4][4];
#pragma unroll
    for (int r = 0; r < 4; ++r)
#pragma unroll
        for (int c = 0; c < 4; ++c) acc[r][c] = (floatx4)0.0f;

    for (int k0 = 0; k0 < K; k0 += 32) {
#pragma unroll
        for (int i = 0; i < 2; ++i) {       // A tile 128 x 32
            int s = tid + i * 256;
            int r = s >> 2, ks = s & 3;
            uint4 d = *(const uint4*)(A + (size_t)(row0 + r) * K + k0 + ks * 8);
            if (BNIN) {
                const __half2* h = (const __half2*)&d;
                uint4 o; __half2* oh = (__half2*)&o;
                int kb = k0 + ks * 8;
#pragma unroll
                for (int j = 0; j < 4; ++j) {
                    float2 f = __half22float2(h[j]);
                    float y0 = fmaxf(0.f, f.x * ssc[kb + 2 * j]     + ssh[kb + 2 * j]);
                    float y1 = fmaxf(0.f, f.y * ssc[kb + 2 * j + 1] + ssh[kb + 2 * j + 1]);
                    oh[j] = __floats2half2_rn(y0, y1);
                }
                d = o;
            }
            *(uint4*)&As[r * LDA + ks * 8] = d;
        }
#pragma unroll
        for (int i = 0; i < 2; ++i) {       // B tile 128 x 32
            int s = tid + i * 256;
            int r = s >> 2, ks = s & 3;
            uint4 d = *(const uint4*)(Wt + (size_t)(col0 + r) * K + k0 + ks * 8);
            *(uint4*)&Bs[r * LDA + ks * 8] = d;
        }
        __syncthreads();
        half8 af[4], bf[4];
#pragma unroll
        for (int r = 0; r < 4; ++r)
            af[r] = *(const half8*)&As[(wr * 64 + r * 16 + l16) * LDA + q * 8];
#pragma unroll
        for (int c = 0; c < 4; ++c)
            bf[c] = *(const half8*)&Bs[(wc * 64 + c * 16 + l16) * LDA + q * 8];
#pragma unroll
        for (int r = 0; r < 4; ++r)
#pragma unroll
            for (int c = 0; c < 4; ++c)
                acc[r][c] = __builtin_amdgcn_mfma_f32_16x16x32_f16(af[r], bf[c], acc[r][c], 0, 0, 0);
        __syncthreads();
    }
    float colsum[4] = {};
    float colsq[4]  = {};
#pragma unroll
    for (int r = 0; r < 4; ++r) {
#pragma unroll
        for (int reg = 0; reg < 4; ++reg) {
            int grow = row0 + wr * 64 + r * 16 + q * 4 + reg;
            float sc = 1.f;
            if (SCALE) sc = (grow < n) ? dinv[grow] : 0.f;
            __half* cp = C + (size_t)grow * NC + col0 + wc * 64 + l16;
#pragma unroll
            for (int c = 0; c < 4; ++c) {
                float v = acc[r][c][reg] * sc;
                cp[c * 16] = __float2half(v);
                if (STATS && grow < n) { colsum[c] += v; colsq[c] += v * v; }
            }
        }
    }
    if (STATS) {
        if (tid < 128) { scs[tid] = 0.f; scq[tid] = 0.f; }
        __syncthreads();
#pragma unroll
        for (int c = 0; c < 4; ++c) {
            atomicAdd(&scs[wc * 64 + c * 16 + l16], colsum[c]);
            atomicAdd(&scq[wc * 64 + c * 16 + l16], colsq[c]);
        }
        __syncthreads();
        if (tid < 128) {
            int slice = blockIdx.x & (NSLICE - 1);
            atomAddF(&osum[slice * 256 + col0 + tid], scs[tid]);
            atomAddF(&osq[slice * 256 + col0 + tid], scq[tid]);
        }
    }
}

// ================= final linear, 128 rows/block, fused BN+ReLU ====================
__global__ __launch_bounds__(256) void k_out(const __half* __restrict__ H,
                                             const float* __restrict__ sums,
                                             const float* __restrict__ sqs,
                                             const float* __restrict__ g,
                                             const float* __restrict__ beta,
                                             const float* __restrict__ Wout,
                                             const float* __restrict__ bout,
                                             float* __restrict__ out, int n) {
    __shared__ float Wl[128 * 10];
    __shared__ float bl[10];
    __shared__ float osc[128];
    __shared__ float osh[128];
    __shared__ float red[256 * 10];
    int tid = threadIdx.x;
    for (int i = tid; i < 1280; i += 256) Wl[i] = Wout[i];
    if (tid < 10) bl[tid] = bout[tid];
    if (tid < 128) {
        float nf = (float)n;
        float su = 0.f, sq = 0.f;
#pragma unroll
        for (int s = 0; s < NSLICE; ++s) {
            su += sums[s * 256 + tid];
            sq += sqs[s * 256 + tid];
        }
        float mu = su / nf;
        float var = sq / nf - mu * mu;
        float sc = g[tid] * rsqrtf(var + EPS_BN);
        osc[tid] = sc; osh[tid] = beta[tid] - mu * sc;
    }
    __syncthreads();
    int rl = tid >> 1;          // 0..127
    int h2 = tid & 1;           // which 64-col half
    int r = blockIdx.x * 128 + rl;
    float p[10] = {};
    if (r < n) {
        const __half* a = H + (size_t)r * 128 + h2 * 64;
#pragma unroll 8
        for (int k = 0; k < 64; ++k) {
            int col = h2 * 64 + k;
            float av = fmaxf(0.f, __half2float(a[k]) * osc[col] + osh[col]);
            const float* wr = Wl + col * 10;
#pragma unroll
            for (int c = 0; c < 10; ++c) p[c] += av * wr[c];
        }
    }
    float* rr = red + (size_t)tid * 10;
#pragma unroll
    for (int c = 0; c < 10; ++c) rr[c] = p[c];
    __syncthreads();
    if (h2 == 0 && r < n) {
        const float* rb = red + (size_t)tid * 10;
#pragma unroll
        for (int c = 0; c < 10; ++c) {
            out[(size_t)r * 10 + c] = rb[c] + rb[10 + c] + bl[c];
        }
    }
}

// ================= launch =================
extern "C" void kernel_launch(void* const* d_in, const int* in_sizes, int n_in,
                              void* d_out, int out_size, void* d_ws, size_t ws_size,
                              hipStream_t stream) {
    const float* x    = (const float*)d_in[0];
    const int*   ei   = (const int*)d_in[1];
    const float* W1   = (const float*)d_in[2];
    const float* g1   = (const float*)d_in[4];
    const float* be1  = (const float*)d_in[5];
    const float* W2   = (const float*)d_in[6];
    const float* g2   = (const float*)d_in[8];
    const float* be2  = (const float*)d_in[9];
    const float* W3   = (const float*)d_in[10];
    const float* g3   = (const float*)d_in[12];
    const float* be3  = (const float*)d_in[13];
    const float* Wout = (const float*)d_in[14];
    const float* bout = (const float*)d_in[15];
    float* out = (float*)d_out;

    int n = in_sizes[0] / 128;
    int E = in_sizes[1] / 2;
    const int* esrc = ei;
    const int* edst = ei + E;
    int npad = cdiv(n, 128) * 128;
    int NBLK = cdiv(E, 4096);
    int NBUCK = (n + 511) >> 9;
    if (NBUCK > 256) return;            // guarantees n <= 131072 (src fits 17 bits)
    int m = NBUCK * NBLK;
    int nb2 = cdiv(m, 1024);
    int sh = 0;
    while ((NCHUNK << sh) < n) ++sh;    // chunk = src >> sh, NCHUNK chunks cover n

    const size_t align = 256;
    auto al = [&](size_t s) { return (s + align - 1) & ~(align - 1); };
    size_t n4  = al((size_t)n * 4 + 512);
    size_t nE8 = al((size_t)n * NCHUNK * 4 + 512);

    const size_t statsLayer = (size_t)NSLICE * 256 * 2 * 4;
    const size_t statsTotal = statsLayer * 3;

    char* ws = (char*)d_ws;
    size_t o_end   = 0;
    size_t o_dinv  = o_end + nE8;
    size_t o_stats = o_dinv + n4;
    size_t o_bsum  = o_stats + statsTotal;
    size_t o_H     = o_bsum + 1024;
    size_t o_Hs    = o_H + al((size_t)m * 4);
    size_t o_csr   = o_Hs + al((size_t)m * 4);
    size_t o_pairs = o_csr + al((size_t)E * 4);
    size_t o_w1    = o_pairs + al((size_t)E * 4);
    size_t o_w2    = o_w1 + al(256 * 128 * 2);
    size_t o_w3    = o_w2 + al(256 * 256 * 2);
    size_t o_A128a = o_w3 + al(128 * 256 * 2);
    size_t o_A128b = o_A128a + al((size_t)npad * 128 * 2);
    size_t o_A256a = o_A128b + al((size_t)npad * 128 * 2);
    size_t o_A256b = o_A256a + al((size_t)npad * 256 * 2);
    size_t need    = o_A256b + (size_t)npad * 256 * 2;
    if (ws_size < need) return;

    int*      endoff = (int*)(ws + o_end);
    float*    dinv   = (float*)(ws + o_dinv);
    float*    stats  = (float*)(ws + o_stats);
    float*    sums1  = stats;
    float*    sqs1   = sums1 + NSLICE * 256;
    float*    sums2  = (float*)(ws + o_stats + statsLayer);
    float*    sqs2   = sums2 + NSLICE * 256;
    float*    sums3  = (float*)(ws + o_stats + 2 * statsLayer);
    float*    sqs3   = sums3 + NSLICE * 256;
    int*      bsum   = (int*)(ws + o_bsum);
    int*      H      = (int*)(ws + o_H);
    int*      Hs     = (int*)(ws + o_Hs);
    int*      csr    = (int*)(ws + o_csr);
    unsigned* pairs  = (unsigned*)(ws + o_pairs);
    __half*   Wt1    = (__half*)(ws + o_w1);
    __half*   Wt2    = (__half*)(ws + o_w2);
    __half*   Wt3    = (__half*)(ws + o_w3);
    __half*   xh     = (__half*)(ws + o_A128a);
    __half*   S3     = (__half*)(ws + o_A128a);
    __half*   G1     = (__half*)(ws + o_A128b);
    __half*   P3     = (__half*)(ws + o_A128b);
    __half*   P1     = (__half*)(ws + o_A256a);
    __half*   S2     = (__half*)(ws + o_A256a);
    __half*   P2     = (__half*)(ws + o_A256b);

    // ---- bucketed CSR build (src-sorted lists, 16 chunks/node) ----
    k_hist<<<NBLK, 256, 0, stream>>>(edst, E, NBLK, NBUCK, H);
    k_scan_reduce<<<nb2, 256, 0, stream>>>(H, m, bsum);
    k_scan_bsum<<<1, 64, 0, stream>>>(bsum, nb2);
    k_scan_final<<<nb2, 256, 0, stream>>>(H, m, bsum, Hs);
    k_bucket<<<NBLK, 256, 0, stream>>>(esrc, edst, E, NBLK, NBUCK, Hs, pairs);
    k_build<<<NBUCK, 256, 0, stream>>>(pairs, Hs, NBLK, NBUCK, n, E, sh, endoff, dinv, csr);

    // ---- prep: x2h + weight transpose + stats zero (one kernel) ----
    int prepTotal = n * 16 + 131072 + NSLICE * 256 * 6;
    k_prep<<<cdiv(prepTotal, 256), 256, 0, stream>>>(
        x, dinv, W1, W2, W3, xh, Wt1, Wt2, Wt3, stats, n);

    int Gn = (n + 31) >> 5;
    int grid128 = 8 * cdiv(Gn, 4);      // 2 slices x 4 XCDs
    int grid256 = 8 * cdiv(Gn, 2);      // 4 slices x 2 XCDs

    // ---- layer 1: G1 = gather(xh); P1 = G1@W1 (+stats1) ----
    k_gather5<128, false><<<grid128, 256, 0, stream>>>(
        csr, endoff, xh, dinv, G1, n, nullptr, nullptr);
    k_gemm_mfma<128, 256, false, false, true><<<dim3(npad / 128, 2), 256, 0, stream>>>(
        G1, Wt1, dinv, nullptr, nullptr, nullptr, nullptr, sums1, sqs1, P1, n);

    // ---- layer 2: P2 = (BN1(P1)@W2)*dinv; S2 = gather(P2) (+stats2) ----
    k_gemm_mfma<256, 256, true, true, false><<<dim3(npad / 128, 2), 256, 0, stream>>>(
        P1, Wt2, dinv, sums1, sqs1, g1, be1, nullptr, nullptr, P2, n);
    k_gather5<256, true><<<grid256, 256, 0, stream>>>(
        csr, endoff, P2, dinv, S2, n, sums2, sqs2);

    // ---- layer 3: P3 = (BN2(S2)@W3)*dinv; S3 = gather(P3) (+stats3) ----
    k_gemm_mfma<256, 128, true, true, false><<<dim3(npad / 128, 1), 256, 0, stream>>>(
        S2, Wt3, dinv, sums2, sqs2, g2, be2, nullptr, nullptr, P3, n);
    k_gather5<128, true><<<grid128, 256, 0, stream>>>(
        csr, endoff, P3, dinv, S3, n, sums3, sqs3);

    // ---- output: out = ReLU(BN3(S3)) @ Wout + bout ----
    k_out<<<cdiv(n, 128), 256, 0, stream>>>(S3, sums3, sqs3, g3, be3, Wout, bout, out, n);
}

// Round 6
// 535.741 us; speedup vs baseline: 1.0456x; 1.0456x over previous
//
#include <hip/hip_runtime.h>
#include <hip/hip_fp16.h>
#include <cstdint>
#include <cstddef>

#define EPS_BN 1e-5f
#define NSLICE 16          // stats accumulator shards (power of 2)
#define NCHUNK 16          // src chunks per neighbor list (power of 2)

static inline int cdiv(int a, int b) { return (a + b - 1) / b; }

using half8   = __attribute__((ext_vector_type(8))) _Float16;
using floatx4 = __attribute__((ext_vector_type(4))) float;

__device__ __forceinline__ float atomAddF(float* p, float v) {
    return unsafeAtomicAdd(p, v);   // HW global_atomic_add_f32 on gfx950
}

// ================= bucketed CSR build (self-loops folded in) =================
// Edge list is logically extended to EL = E + n with self edges (v,v) so the
// gather's self-term rides the sorted-window stream instead of a separate
// 51MB pass over P. bucket = dst >> 9; NBUCK <= 256 (n <= 131072) required.
// pairs[] entries: (dstLow9 << 17) | src17.
// csr sub-sorted by (dst, src>>sh): 16 chunks/node, endoff[v*16+c] = cum. end.

__global__ __launch_bounds__(256) void k_hist(const int* __restrict__ dst, int E, int EL,
                                              int NBLK, int NBUCK, int* __restrict__ H) {
    __shared__ int h[256];
    int t = threadIdx.x;
    h[t] = 0;
    __syncthreads();
    int base = blockIdx.x * 4096;
#pragma unroll
    for (int j = 0; j < 16; ++j) {
        int e = base + j * 256 + t;
        if (e < EL) {
            int d = (e < E) ? dst[e] : (e - E);
            atomicAdd(&h[d >> 9], 1);
        }
    }
    __syncthreads();
    if (t < NBUCK) H[t * NBLK + blockIdx.x] = h[t];
}

__global__ __launch_bounds__(256) void k_scan_reduce(const int* __restrict__ in, int m,
                                                     int* __restrict__ bsum) {
    int base = blockIdx.x * 1024;
    int t = threadIdx.x;
    int s = 0;
#pragma unroll
    for (int i = 0; i < 4; ++i) {
        int idx = base + t * 4 + i;
        if (idx < m) s += in[idx];
    }
    __shared__ int sm[256];
    sm[t] = s;
    __syncthreads();
    for (int off = 128; off > 0; off >>= 1) {
        if (t < off) sm[t] += sm[t + off];
        __syncthreads();
    }
    if (t == 0) bsum[blockIdx.x] = sm[0];
}

__global__ void k_scan_bsum(int* __restrict__ bsum, int nb) {
    if (threadIdx.x == 0 && blockIdx.x == 0) {
        int acc = 0;
        for (int i = 0; i < nb; ++i) { int v = bsum[i]; bsum[i] = acc; acc += v; }
    }
}

__global__ __launch_bounds__(256) void k_scan_final(const int* __restrict__ in, int m,
                                                    const int* __restrict__ bsum,
                                                    int* __restrict__ outS) {
    int base = blockIdx.x * 1024;
    int t = threadIdx.x;
    int v[4];
    int s = 0;
#pragma unroll
    for (int i = 0; i < 4; ++i) {
        int idx = base + t * 4 + i;
        v[i] = (idx < m) ? in[idx] : 0;
        s += v[i];
    }
    __shared__ int sm[256];
    sm[t] = s;
    __syncthreads();
    for (int off = 1; off < 256; off <<= 1) {
        int x = (t >= off) ? sm[t - off] : 0;
        __syncthreads();
        sm[t] += x;
        __syncthreads();
    }
    int excl = sm[t] - s + bsum[blockIdx.x];
#pragma unroll
    for (int i = 0; i < 4; ++i) {
        int idx = base + t * 4 + i;
        if (idx < m) { outS[idx] = excl; excl += v[i]; }
    }
}

__global__ __launch_bounds__(256) void k_bucket(const int* __restrict__ src,
                                                const int* __restrict__ dst, int E, int EL,
                                                int NBLK, int NBUCK,
                                                const int* __restrict__ S,
                                                unsigned* __restrict__ pairs) {
    __shared__ int cur[256];
    int t = threadIdx.x;
    if (t < NBUCK) cur[t] = S[t * NBLK + blockIdx.x];
    __syncthreads();
    int base = blockIdx.x * 4096;
#pragma unroll
    for (int j = 0; j < 16; ++j) {
        int e = base + j * 256 + t;
        if (e < EL) {
            unsigned s, d;
            if (e < E) { s = (unsigned)src[e]; d = (unsigned)dst[e]; }
            else       { s = d = (unsigned)(e - E); }          // self edge
            int p = atomicAdd(&cur[d >> 9], 1);
            pairs[p] = ((d & 511u) << 17) | s;
        }
    }
}

// counting sort by key = (dstLow9 << 4) | (src >> sh); 8192 keys per bucket.
__global__ __launch_bounds__(256) void k_build(const unsigned* __restrict__ pairs,
                                               const int* __restrict__ S,
                                               int NBLK, int NBUCK, int n, int EL, int sh,
                                               int* __restrict__ endoff,
                                               float* __restrict__ dinv,
                                               int* __restrict__ csr) {
    int b = blockIdx.x;
    int nbase = b << 9;
    int bstart = S[b * NBLK];
    int bend = (b == NBUCK - 1) ? EL : S[(b + 1) * NBLK];
    int t = threadIdx.x;
    __shared__ int sdeg[8192];
    __shared__ int scur[8192];
    __shared__ int stmp[256];
#pragma unroll
    for (int i = 0; i < 32; ++i) sdeg[t + i * 256] = 0;
    __syncthreads();
    for (int e = bstart + t; e < bend; e += 256) {
        unsigned p = pairs[e];
        int key = (int)((p >> 17) << 4) | (int)((p & 0x1FFFFu) >> sh);
        atomicAdd(&sdeg[key], 1);
    }
    __syncthreads();
    int loc[32];
    int ls = 0;
#pragma unroll
    for (int i = 0; i < 32; ++i) { loc[i] = sdeg[t * 32 + i]; ls += loc[i]; }
    stmp[t] = ls;
    __syncthreads();
    for (int off = 1; off < 256; off <<= 1) {
        int x = (t >= off) ? stmp[t - off] : 0;
        __syncthreads();
        stmp[t] += x;
        __syncthreads();
    }
    int run = bstart + stmp[t] - ls;
    int d0 = 0, d1 = 0;
    int v0 = nbase + 2 * t, v1 = v0 + 1;
#pragma unroll
    for (int i = 0; i < 32; ++i) {
        scur[t * 32 + i] = run;
        int e_ = run + loc[i];
        int v = (i < 16) ? v0 : v1;
        if (v < n) endoff[(size_t)v * NCHUNK + (i & 15)] = e_;
        run = e_;
        if (i < 16) d0 += loc[i]; else d1 += loc[i];
    }
    // self edge already counted in d0/d1 -> deg_with_self
    if (v0 < n) dinv[v0] = rsqrtf((float)d0);
    if (v1 < n) dinv[v1] = rsqrtf((float)d1);
    __syncthreads();
    for (int e = bstart + t; e < bend; e += 256) {
        unsigned p = pairs[e];
        int key = (int)((p >> 17) << 4) | (int)((p & 0x1FFFFu) >> sh);
        int pos = atomicAdd(&scur[key], 1);
        csr[pos] = (int)(p & 0x1FFFFu);
    }
}

// ================= prep: x->f16*dinv, weights->f16 transposed, stats zero ========
__global__ __launch_bounds__(256) void k_prep(const float* __restrict__ x,
                                              const float* __restrict__ dinv,
                                              const float* __restrict__ W1,
                                              const float* __restrict__ W2,
                                              const float* __restrict__ W3,
                                              __half* __restrict__ xh,
                                              __half* __restrict__ Wt1,
                                              __half* __restrict__ Wt2,
                                              __half* __restrict__ Wt3,
                                              float* __restrict__ stats, int n) {
    int idx = blockIdx.x * 256 + threadIdx.x;
    int nx = n * 16;
    if (idx < nx) {                          // x -> f16, pre-scaled by dinv (8-half chunks)
        int row = idx >> 4;
        float dv = dinv[row];
        const float4* p = (const float4*)x + (size_t)idx * 2;
        float4 a = p[0], b = p[1];
        uint4 o; __half2* oh = (__half2*)&o;
        oh[0] = __floats2half2_rn(a.x * dv, a.y * dv);
        oh[1] = __floats2half2_rn(a.z * dv, a.w * dv);
        oh[2] = __floats2half2_rn(b.x * dv, b.y * dv);
        oh[3] = __floats2half2_rn(b.z * dv, b.w * dv);
        ((uint4*)xh)[idx] = o;
        return;
    }
    int r = idx - nx;
    if (r < 32768) {                         // W1: 128x256
        int k = r >> 8, c = r & 255;
        Wt1[c * 128 + k] = __float2half(W1[r]);
    } else if (r < 98304) {                  // W2: 256x256
        int r2 = r - 32768;
        int k = r2 >> 8, c = r2 & 255;
        Wt2[c * 256 + k] = __float2half(W2[r2]);
    } else if (r < 131072) {                 // W3: 256x128
        int r2 = r - 98304;
        int k = r2 >> 7, c = r2 & 127;
        Wt3[c * 256 + k] = __float2half(W3[r2]);
    } else if (r < 131072 + NSLICE * 256 * 6) {
        stats[r - 131072] = 0.f;             // zero all 3 layers' sliced sums/sqs
    }
}

// ================= CSR gather, feature-sliced, self-loop folded ================
// csr lists sorted by src>>sh -> linear walk reads monotone src windows; self
// edge is inside the list (chunk v>>sh) so no separate self-stream. Cached
// (non-NT) loads everywhere: R5 showed NT costs rate for ~no byte savings.
__device__ __forceinline__ void acc8(float* acc, uint4 d) {
    const __half2* h = (const __half2*)&d;
#pragma unroll
    for (int j = 0; j < 4; ++j) {
        float2 f = __half22float2(h[j]);
        acc[2 * j] += f.x; acc[2 * j + 1] += f.y;
    }
}

template<int D>
__device__ __forceinline__ void gseg(const __half* __restrict__ Pb,
                                     const int* __restrict__ csr,
                                     int i, int end, float* acc) {
    int rem = (end - i) & 3;
    if (rem & 2) {
        uint4 d0 = *(const uint4*)(Pb + (size_t)csr[i] * D);
        uint4 d1 = *(const uint4*)(Pb + (size_t)csr[i + 1] * D);
        acc8(acc, d0); acc8(acc, d1);
        i += 2;
    }
    if (rem & 1) {
        uint4 d0 = *(const uint4*)(Pb + (size_t)csr[i] * D);
        acc8(acc, d0);
        ++i;
    }
    if (i < end) {                           // multiple of 4 remaining
        uint4 a[4];
#pragma unroll
        for (int u = 0; u < 4; ++u)
            a[u] = *(const uint4*)(Pb + (size_t)csr[i + u] * D);
        for (i += 4; i < end; i += 4) {
            uint4 b[4];
#pragma unroll
            for (int u = 0; u < 4; ++u)
                b[u] = *(const uint4*)(Pb + (size_t)csr[i + u] * D);
#pragma unroll
            for (int u = 0; u < 4; ++u) acc8(acc, a[u]);
#pragma unroll
            for (int u = 0; u < 4; ++u) a[u] = b[u];
        }
#pragma unroll
        for (int u = 0; u < 4; ++u) acc8(acc, a[u]);
    }
}

template<int D, bool STATS>
__global__ __launch_bounds__(256, 8) void k_gather6(const int* __restrict__ csr,
                                                    const int* __restrict__ endoff,
                                                    const __half* __restrict__ P,
                                                    const float* __restrict__ dinv,
                                                    __half* __restrict__ S, int n,
                                                    float* __restrict__ sums,
                                                    float* __restrict__ sqs) {
    constexpr int NSL = D / 64;              // 128B slices per row (2 or 4)
    __shared__ float red[STATS ? 2048 : 1];
    int bid = blockIdx.x;
    int x8 = bid & 7;
    int slice, gidx;
    if (NSL == 4) { slice = x8 >> 1; gidx = (bid >> 3) * 2 + (x8 & 1); }
    else          { slice = x8 >> 2; gidx = (bid >> 3) * 4 + (x8 & 3); }
    int Gn = (n + 31) >> 5;
    if (gidx >= Gn) return;                  // whole block exits (uniform)
    int t = threadIdx.x;
    int lane = t & 7;                        // 16B sub-slice within 128B
    int sub = t >> 3;                        // node within block (32 nodes)
    int v = gidx * 32 + sub;
    // clock-phased start window: ~1us per window at 100MHz REFCLK
    int c0 = (int)((wall_clock64() / 100ull) & (unsigned long long)(NCHUNK - 1));
    const __half* Pb = P + (size_t)slice * 64 + lane * 8;
    float ov[8];
#pragma unroll
    for (int j = 0; j < 8; ++j) ov[j] = 0.f;
    if (v < n) {
        float acc[8] = {};
        size_t i0 = (size_t)v * NCHUNK;
        int beg = (i0 == 0) ? 0 : endoff[i0 - 1];
        int end = endoff[i0 + NCHUNK - 1];
        int mid = (c0 == 0) ? beg : endoff[i0 + c0 - 1];
        gseg<D>(Pb, csr, mid, end, acc);     // [mid, end)
        gseg<D>(Pb, csr, beg, mid, acc);     // [beg, mid)
        float dv = dinv[v];
        uint4 o; __half2* oh = (__half2*)&o;
#pragma unroll
        for (int j = 0; j < 4; ++j) {
            float a0 = acc[2 * j] * dv, a1 = acc[2 * j + 1] * dv;
            oh[j] = __floats2half2_rn(a0, a1);
            ov[2 * j] = a0; ov[2 * j + 1] = a1;
        }
        *(uint4*)(S + (size_t)v * D + slice * 64 + lane * 8) = o;
    }
    if (STATS) {
        int shard = bid & (NSLICE - 1);
#pragma unroll
        for (int j = 0; j < 8; ++j) red[t * 8 + j] = ov[j];
        __syncthreads();
        if (t < 64) {                        // col-in-slice = t = lane*8+j
            int ln = t >> 3, j = t & 7;
            float ts = 0.f;
#pragma unroll
            for (int s = 0; s < 32; ++s) ts += red[(s * 8 + ln) * 8 + j];
            atomAddF(&sums[shard * 256 + slice * 64 + t], ts);
        }
        __syncthreads();
#pragma unroll
        for (int j = 0; j < 8; ++j) red[t * 8 + j] = ov[j] * ov[j];
        __syncthreads();
        if (t < 64) {
            int ln = t >> 3, j = t & 7;
            float tq = 0.f;
#pragma unroll
            for (int s = 0; s < 32; ++s) tq += red[(s * 8 + ln) * 8 + j];
            atomAddF(&sqs[shard * 256 + slice * 64 + t], tq);
        }
    }
}

// ================= MFMA GEMM: 128xNC tile per block, 2x(NC/64) waves ===========
// Full output width per block: A panel staged ONCE (was fetched twice from HBM
// for NC=256 since the paired col-blocks landed on different XCDs).
// Per-wave shape unchanged: 64x64, acc[4][4], 16 MFMA per K-step.
template<int K, int NC, bool SCALE, bool BNIN, bool STATS>
__global__ __launch_bounds__(2 * NC) void k_gemm_mfma(const __half* __restrict__ A,
                                                   const __half* __restrict__ Wt,
                                                   const float* __restrict__ dinv,
                                                   const float* __restrict__ isum,
                                                   const float* __restrict__ isq,
                                                   const float* __restrict__ g,
                                                   const float* __restrict__ beta,
                                                   float* __restrict__ osum,
                                                   float* __restrict__ osq,
                                                   __half* __restrict__ C, int n) {
    constexpr int THREADS = 2 * NC;          // 512 (NC=256) or 256 (NC=128)
    constexpr int CW = NC / 64;              // col-waves: 4 or 2
    constexpr int LDA = 40;
    __shared__ _Float16 As[128 * LDA];
    __shared__ _Float16 Bs[NC * LDA];
    __shared__ float ssc[BNIN ? K : 1];
    __shared__ float ssh[BNIN ? K : 1];
    __shared__ float scs[STATS ? NC : 1];
    __shared__ float scq[STATS ? NC : 1];
    int tid = threadIdx.x;
    if (BNIN) {
        float nf = (float)n;
        for (int i = tid; i < K; i += THREADS) {
            float su = 0.f, sq = 0.f;
#pragma unroll
            for (int s = 0; s < NSLICE; ++s) {
                su += isum[s * 256 + i];
                sq += isq[s * 256 + i];
            }
            float mu = su / nf;
            float var = sq / nf - mu * mu;
            float sc = g[i] * rsqrtf(var + EPS_BN);
            ssc[i] = sc; ssh[i] = beta[i] - mu * sc;
        }
        __syncthreads();
    }
    int wave = tid >> 6, lane = tid & 63;
    int wr = wave / CW, wc = wave % CW;      // 2 x CW wave grid, 64x64 per wave
    int q = lane >> 4, l16 = lane & 15;
    int row0 = blockIdx.x * 128;
    floatx4 acc[4][4];
#pragma unroll
    for (int r = 0; r < 4; ++r)
#pragma unroll
        for (int c = 0; c < 4; ++c) acc[r][c] = (floatx4)0.0f;

    for (int k0 = 0; k0 < K; k0 += 32) {
        constexpr int AIT = 512 / THREADS;  // A tile 128x32 = 512 16B-chunks
#pragma unroll
        for (int i = 0; i < AIT; ++i) {
            int s = tid + i * THREADS;
            int r = s >> 2, ks = s & 3;
            uint4 d = *(const uint4*)(A + (size_t)(row0 + r) * K + k0 + ks * 8);
            if (BNIN) {
                const __half2* h = (const __half2*)&d;
                uint4 o; __half2* oh = (__half2*)&o;
                int kb = k0 + ks * 8;
#pragma unroll
                for (int j = 0; j < 4; ++j) {
                    float2 f = __half22float2(h[j]);
                    float y0 = fmaxf(0.f, f.x * ssc[kb + 2 * j]     + ssh[kb + 2 * j]);
                    float y1 = fmaxf(0.f, f.y * ssc[kb + 2 * j + 1] + ssh[kb + 2 * j + 1]);
                    oh[j] = __floats2half2_rn(y0, y1);
                }
                d = o;
            }
            *(uint4*)&As[r * LDA + ks * 8] = d;
        }
        constexpr int BIT = NC * 4 / THREADS;  // B tile NCx32
#pragma unroll
        for (int i = 0; i < BIT; ++i) {
            int s = tid + i * THREADS;
            int r = s >> 2, ks = s & 3;
            uint4 d = *(const uint4*)(Wt + (size_t)r * K + k0 + ks * 8);
            *(uint4*)&Bs[r * LDA + ks * 8] = d;
        }
        __syncthreads();
        half8 af[4], bf[4];
#pragma unroll
        for (int r = 0; r < 4; ++r)
            af[r] = *(const half8*)&As[(wr * 64 + r * 16 + l16) * LDA + q * 8];
#pragma unroll
        for (int c = 0; c < 4; ++c)
            bf[c] = *(const half8*)&Bs[(wc * 64 + c * 16 + l16) * LDA + q * 8];
#pragma unroll
        for (int r = 0; r < 4; ++r)
#pragma unroll
            for (int c = 0; c < 4; ++c)
                acc[r][c] = __builtin_amdgcn_mfma_f32_16x16x32_f16(af[r], bf[c], acc[r][c], 0, 0, 0);
        __syncthreads();
    }
    float colsum[4] = {};
    float colsq[4]  = {};
#pragma unroll
    for (int r = 0; r < 4; ++r) {
#pragma unroll
        for (int reg = 0; reg < 4; ++reg) {
            int grow = row0 + wr * 64 + r * 16 + q * 4 + reg;
            float sc = 1.f;
            if (SCALE) sc = (grow < n) ? dinv[grow] : 0.f;
            __half* cp = C + (size_t)grow * NC + wc * 64 + l16;
#pragma unroll
            for (int c = 0; c < 4; ++c) {
                float v = acc[r][c][reg] * sc;
                cp[c * 16] = __float2half(v);
                if (STATS && grow < n) { colsum[c] += v; colsq[c] += v * v; }
            }
        }
    }
    if (STATS) {
        if (tid < NC) { scs[tid] = 0.f; scq[tid] = 0.f; }
        __syncthreads();
#pragma unroll
        for (int c = 0; c < 4; ++c) {
            atomicAdd(&scs[wc * 64 + c * 16 + l16], colsum[c]);
            atomicAdd(&scq[wc * 64 + c * 16 + l16], colsq[c]);
        }
        __syncthreads();
        if (tid < NC) {
            int slice = blockIdx.x & (NSLICE - 1);
            atomAddF(&osum[slice * 256 + tid], scs[tid]);
            atomAddF(&osq[slice * 256 + tid], scq[tid]);
        }
    }
}

// ================= final linear, 128 rows/block, fused BN+ReLU ====================
__global__ __launch_bounds__(256) void k_out(const __half* __restrict__ H,
                                             const float* __restrict__ sums,
                                             const float* __restrict__ sqs,
                                             const float* __restrict__ g,
                                             const float* __restrict__ beta,
                                             const float* __restrict__ Wout,
                                             const float* __restrict__ bout,
                                             float* __restrict__ out, int n) {
    __shared__ float Wl[128 * 10];
    __shared__ float bl[10];
    __shared__ float osc[128];
    __shared__ float osh[128];
    __shared__ float red[256 * 10];
    int tid = threadIdx.x;
    for (int i = tid; i < 1280; i += 256) Wl[i] = Wout[i];
    if (tid < 10) bl[tid] = bout[tid];
    if (tid < 128) {
        float nf = (float)n;
        float su = 0.f, sq = 0.f;
#pragma unroll
        for (int s = 0; s < NSLICE; ++s) {
            su += sums[s * 256 + tid];
            sq += sqs[s * 256 + tid];
        }
        float mu = su / nf;
        float var = sq / nf - mu * mu;
        float sc = g[tid] * rsqrtf(var + EPS_BN);
        osc[tid] = sc; osh[tid] = beta[tid] - mu * sc;
    }
    __syncthreads();
    int rl = tid >> 1;          // 0..127
    int h2 = tid & 1;           // which 64-col half
    int r = blockIdx.x * 128 + rl;
    float p[10] = {};
    if (r < n) {
        const __half* a = H + (size_t)r * 128 + h2 * 64;
#pragma unroll 8
        for (int k = 0; k < 64; ++k) {
            int col = h2 * 64 + k;
            float av = fmaxf(0.f, __half2float(a[k]) * osc[col] + osh[col]);
            const float* wr = Wl + col * 10;
#pragma unroll
            for (int c = 0; c < 10; ++c) p[c] += av * wr[c];
        }
    }
    float* rr = red + (size_t)tid * 10;
#pragma unroll
    for (int c = 0; c < 10; ++c) rr[c] = p[c];
    __syncthreads();
    if (h2 == 0 && r < n) {
        const float* rb = red + (size_t)tid * 10;
#pragma unroll
        for (int c = 0; c < 10; ++c) {
            out[(size_t)r * 10 + c] = rb[c] + rb[10 + c] + bl[c];
        }
    }
}

// ================= launch =================
extern "C" void kernel_launch(void* const* d_in, const int* in_sizes, int n_in,
                              void* d_out, int out_size, void* d_ws, size_t ws_size,
                              hipStream_t stream) {
    const float* x    = (const float*)d_in[0];
    const int*   ei   = (const int*)d_in[1];
    const float* W1   = (const float*)d_in[2];
    const float* g1   = (const float*)d_in[4];
    const float* be1  = (const float*)d_in[5];
    const float* W2   = (const float*)d_in[6];
    const float* g2   = (const float*)d_in[8];
    const float* be2  = (const float*)d_in[9];
    const float* W3   = (const float*)d_in[10];
    const float* g3   = (const float*)d_in[12];
    const float* be3  = (const float*)d_in[13];
    const float* Wout = (const float*)d_in[14];
    const float* bout = (const float*)d_in[15];
    float* out = (float*)d_out;

    int n = in_sizes[0] / 128;
    int E = in_sizes[1] / 2;
    const int* esrc = ei;
    const int* edst = ei + E;
    int EL = E + n;                     // edges + folded self-loops
    int npad = cdiv(n, 128) * 128;
    int NBLK = cdiv(EL, 4096);
    int NBUCK = (n + 511) >> 9;
    if (NBUCK > 256) return;            // guarantees n <= 131072 (src fits 17 bits)
    int m = NBUCK * NBLK;
    int nb2 = cdiv(m, 1024);
    int sh = 0;
    while ((NCHUNK << sh) < n) ++sh;    // chunk = src >> sh, NCHUNK chunks cover n

    const size_t align = 256;
    auto al = [&](size_t s) { return (s + align - 1) & ~(align - 1); };
    size_t n4  = al((size_t)n * 4 + 512);
    size_t nE8 = al((size_t)n * NCHUNK * 4 + 512);

    const size_t statsLayer = (size_t)NSLICE * 256 * 2 * 4;
    const size_t statsTotal = statsLayer * 3;

    char* ws = (char*)d_ws;
    size_t o_end   = 0;
    size_t o_dinv  = o_end + nE8;
    size_t o_stats = o_dinv + n4;
    size_t o_bsum  = o_stats + statsTotal;
    size_t o_H     = o_bsum + 1024;
    size_t o_Hs    = o_H + al((size_t)m * 4);
    size_t o_csr   = o_Hs + al((size_t)m * 4);
    size_t o_pairs = o_csr + al((size_t)EL * 4);
    size_t o_w1    = o_pairs + al((size_t)EL * 4);
    size_t o_w2    = o_w1 + al(256 * 128 * 2);
    size_t o_w3    = o_w2 + al(256 * 256 * 2);
    size_t o_A128a = o_w3 + al(128 * 256 * 2);
    size_t o_A128b = o_A128a + al((size_t)npad * 128 * 2);
    size_t o_A256a = o_A128b + al((size_t)npad * 128 * 2);
    size_t o_A256b = o_A256a + al((size_t)npad * 256 * 2);
    size_t need    = o_A256b + (size_t)npad * 256 * 2;
    if (ws_size < need) return;

    int*      endoff = (int*)(ws + o_end);
    float*    dinv   = (float*)(ws + o_dinv);
    float*    stats  = (float*)(ws + o_stats);
    float*    sums1  = stats;
    float*    sqs1   = sums1 + NSLICE * 256;
    float*    sums2  = (float*)(ws + o_stats + statsLayer);
    float*    sqs2   = sums2 + NSLICE * 256;
    float*    sums3  = (float*)(ws + o_stats + 2 * statsLayer);
    float*    sqs3   = sums3 + NSLICE * 256;
    int*      bsum   = (int*)(ws + o_bsum);
    int*      H      = (int*)(ws + o_H);
    int*      Hs     = (int*)(ws + o_Hs);
    int*      csr    = (int*)(ws + o_csr);
    unsigned* pairs  = (unsigned*)(ws + o_pairs);
    __half*   Wt1    = (__half*)(ws + o_w1);
    __half*   Wt2    = (__half*)(ws + o_w2);
    __half*   Wt3    = (__half*)(ws + o_w3);
    __half*   xh     = (__half*)(ws + o_A128a);
    __half*   S3     = (__half*)(ws + o_A128a);
    __half*   G1     = (__half*)(ws + o_A128b);
    __half*   P3     = (__half*)(ws + o_A128b);
    __half*   P1     = (__half*)(ws + o_A256a);
    __half*   S2     = (__half*)(ws + o_A256a);
    __half*   P2     = (__half*)(ws + o_A256b);

    // ---- bucketed CSR build (self-loops folded, src-sorted, 16 chunks/node) ----
    k_hist<<<NBLK, 256, 0, stream>>>(edst, E, EL, NBLK, NBUCK, H);
    k_scan_reduce<<<nb2, 256, 0, stream>>>(H, m, bsum);
    k_scan_bsum<<<1, 64, 0, stream>>>(bsum, nb2);
    k_scan_final<<<nb2, 256, 0, stream>>>(H, m, bsum, Hs);
    k_bucket<<<NBLK, 256, 0, stream>>>(esrc, edst, E, EL, NBLK, NBUCK, Hs, pairs);
    k_build<<<NBUCK, 256, 0, stream>>>(pairs, Hs, NBLK, NBUCK, n, EL, sh, endoff, dinv, csr);

    // ---- prep: x2h + weight transpose + stats zero (one kernel) ----
    int prepTotal = n * 16 + 131072 + NSLICE * 256 * 6;
    k_prep<<<cdiv(prepTotal, 256), 256, 0, stream>>>(
        x, dinv, W1, W2, W3, xh, Wt1, Wt2, Wt3, stats, n);

    int Gn = (n + 31) >> 5;
    int grid128 = 8 * cdiv(Gn, 4);      // 2 slices x 4 XCDs
    int grid256 = 8 * cdiv(Gn, 2);      // 4 slices x 2 XCDs

    // ---- layer 1: G1 = gather(xh); P1 = G1@W1 (+stats1) ----
    k_gather6<128, false><<<grid128, 256, 0, stream>>>(
        csr, endoff, xh, dinv, G1, n, nullptr, nullptr);
    k_gemm_mfma<128, 256, false, false, true><<<dim3(npad / 128), 512, 0, stream>>>(
        G1, Wt1, dinv, nullptr, nullptr, nullptr, nullptr, sums1, sqs1, P1, n);

    // ---- layer 2: P2 = (BN1(P1)@W2)*dinv; S2 = gather(P2) (+stats2) ----
    k_gemm_mfma<256, 256, true, true, false><<<dim3(npad / 128), 512, 0, stream>>>(
        P1, Wt2, dinv, sums1, sqs1, g1, be1, nullptr, nullptr, P2, n);
    k_gather6<256, true><<<grid256, 256, 0, stream>>>(
        csr, endoff, P2, dinv, S2, n, sums2, sqs2);

    // ---- layer 3: P3 = (BN2(S2)@W3)*dinv; S3 = gather(P3) (+stats3) ----
    k_gemm_mfma<256, 128, true, true, false><<<dim3(npad / 128), 256, 0, stream>>>(
        S2, Wt3, dinv, sums2, sqs2, g2, be2, nullptr, nullptr, P3, n);
    k_gather6<128, true><<<grid128, 256, 0, stream>>>(
        csr, endoff, P3, dinv, S3, n, sums3, sqs3);

    // ---- output: out = ReLU(BN3(S3)) @ Wout + bout ----
    k_out<<<cdiv(n, 128), 256, 0, stream>>>(S3, sums3, sqs3, g3, be3, Wout, bout, out, n);
}